// Round 1
// baseline (403.224 us; speedup 1.0000x reference)
//
#include <hip/hip_runtime.h>
#include <hip/hip_bf16.h>

// Problem constants (SoftMoEGating: B=8, S=4096, D=1024, E=8, P=4, K=E*P=32)
#define B 8
#define S 4096
#define D 1024
#define KK 32   // E*P

// ---------------------------------------------------------------------------
// K1: logits[b,s,k] = dot(x[b,s,:], phi[:,k]) + bias[k]
// grid 512 (= B*S/64), block 256. Each block: 64 tokens, all 32 k.
// Wave w owns k in [8w, 8w+8); lane = token. x tile staged in LDS (stride 133
// -> conflict-free b32 column reads). phi read wave-uniformly (-> s_load).
// ---------------------------------------------------------------------------
__global__ __launch_bounds__(256) void k1_logits(const float* __restrict__ x,
                                                 const float* __restrict__ phi,
                                                 const float* __restrict__ bias,
                                                 float* __restrict__ logits) {
    __shared__ float xt[64][133];
    const int b  = blockIdx.x >> 6;        // 64 blocks per batch
    const int s0 = (blockIdx.x & 63) * 64;
    const int tid = threadIdx.x;
    const int kg = __builtin_amdgcn_readfirstlane(tid >> 6);  // wave-uniform
    const int sg = tid & 63;

    float acc[8];
#pragma unroll
    for (int j = 0; j < 8; ++j) acc[j] = bias[kg * 8 + j];

    const float* xb = x + ((size_t)b * S + s0) * D;

    for (int dc = 0; dc < D; dc += 128) {
        __syncthreads();
        // stage 64 tokens x 128 d (coalesced float4 reads)
#pragma unroll
        for (int i = 0; i < 8; ++i) {
            int f   = tid + i * 256;       // 0..2047 float4 slots
            int row = f >> 5;              // token row 0..63
            int c4  = f & 31;              // float4 col 0..31
            float4 v = ((const float4*)(xb + (size_t)row * D + dc))[c4];
            xt[row][c4 * 4 + 0] = v.x;
            xt[row][c4 * 4 + 1] = v.y;
            xt[row][c4 * 4 + 2] = v.z;
            xt[row][c4 * 4 + 3] = v.w;
        }
        __syncthreads();

        const float* prow = phi + (size_t)dc * KK + kg * 8;  // wave-uniform
#pragma unroll 4
        for (int d = 0; d < 128; ++d) {
            float xv = xt[sg][d];
#pragma unroll
            for (int j = 0; j < 8; ++j) acc[j] += xv * prow[d * KK + j];
        }
    }

    float* lrow = logits + ((size_t)b * S + s0 + sg) * KK + kg * 8;
#pragma unroll
    for (int j = 0; j < 8; ++j) lrow[j] = acc[j];
}

// ---------------------------------------------------------------------------
// K2: softmax over S per (b,k); writes phi_weights straight into d_out region.
// grid 256 (= B*KK), block 256; 16 logits/thread kept in registers.
// ---------------------------------------------------------------------------
__global__ __launch_bounds__(256) void k2_softmax(const float* __restrict__ logits,
                                                  float* __restrict__ pw_out) {
    const int b = blockIdx.x >> 5;
    const int k = blockIdx.x & 31;
    const int tid = threadIdx.x;
    const int wave = tid >> 6, lane = tid & 63;

    const float* lp = logits + (size_t)b * S * KK + k;
    float* wp = pw_out + (size_t)b * S * KK + k;

    float v[16];
    float m = -1e30f;
#pragma unroll
    for (int i = 0; i < 16; ++i) {
        v[i] = lp[(size_t)(tid + i * 256) * KK];
        m = fmaxf(m, v[i]);
    }
#pragma unroll
    for (int off = 32; off >= 1; off >>= 1) m = fmaxf(m, __shfl_xor(m, off, 64));

    __shared__ float redm[4];
    __shared__ float reds[4];
    if (lane == 0) redm[wave] = m;
    __syncthreads();
    m = fmaxf(fmaxf(redm[0], redm[1]), fmaxf(redm[2], redm[3]));

    float s = 0.f;
#pragma unroll
    for (int i = 0; i < 16; ++i) {
        v[i] = __expf(v[i] - m);
        s += v[i];
    }
#pragma unroll
    for (int off = 32; off >= 1; off >>= 1) s += __shfl_xor(s, off, 64);
    if (lane == 0) reds[wave] = s;
    __syncthreads();
    s = reds[0] + reds[1] + reds[2] + reds[3];

    float r = 1.0f / s;
#pragma unroll
    for (int i = 0; i < 16; ++i) wp[(size_t)(tid + i * 256) * KK] = v[i] * r;
}

// ---------------------------------------------------------------------------
// K3: partial soft_slots. grid 256 = b(8) x dtile(4 of 256) x schunk(8 of 512).
// Thread: wave-uniform kg owns 8 k, lane owns 4 consecutive d (float4).
// Inner: 1 coalesced float4 x-load + 8 uniform w loads + 32 FMA.
// part[sc][b][k][d] written to workspace (no atomics).
// ---------------------------------------------------------------------------
__global__ __launch_bounds__(256) void k3_partial(const float* __restrict__ x,
                                                  const float* __restrict__ pw,
                                                  float* __restrict__ part) {
    const int bid = blockIdx.x;
    const int b  = bid >> 5;
    const int dt = (bid >> 3) & 3;
    const int sc = bid & 7;
    const int tid = threadIdx.x;
    const int kg = __builtin_amdgcn_readfirstlane(tid >> 6);
    const int dg = tid & 63;

    float4 acc[8];
#pragma unroll
    for (int j = 0; j < 8; ++j) acc[j] = make_float4(0.f, 0.f, 0.f, 0.f);

    const float* xb = x + ((size_t)b * S + sc * 512) * D + dt * 256 + dg * 4;
    const float* wb = pw + ((size_t)b * S + sc * 512) * KK + kg * 8;

#pragma unroll 2
    for (int s = 0; s < 512; ++s) {
        float4 xv = *(const float4*)(xb + (size_t)s * D);
#pragma unroll
        for (int j = 0; j < 8; ++j) {
            float w = wb[s * KK + j];
            acc[j].x += w * xv.x;
            acc[j].y += w * xv.y;
            acc[j].z += w * xv.z;
            acc[j].w += w * xv.w;
        }
    }

    float* pp = part + (((size_t)sc * B + b) * KK + kg * 8) * D + dt * 256 + dg * 4;
#pragma unroll
    for (int j = 0; j < 8; ++j) *(float4*)(pp + (size_t)j * D) = acc[j];
}

// ---------------------------------------------------------------------------
// K4: reduce 8 partials -> soft_slots + expert_inputs; fill expert_weights
// (0.125) and expert_indices (0..7 as float). grid 256, block 256, float4 each.
// ---------------------------------------------------------------------------
__global__ __launch_bounds__(256) void k4_finalize(const float* __restrict__ part,
                                                   float* __restrict__ out) {
    const int idx = blockIdx.x * 256 + threadIdx.x;  // 0..65535 float4 slots
    const float4* p4 = (const float4*)part;

    float4 sv = p4[idx];
#pragma unroll
    for (int c = 1; c < 8; ++c) {
        float4 t = p4[(size_t)c * 65536 + idx];
        sv.x += t.x; sv.y += t.y; sv.z += t.z; sv.w += t.w;
    }

    // out layout (floats): ew[0..262144) ei[262144..524288) pw[524288..1572864)
    //                      ss[1572864..1835008) einp[1835008..2097152)
    ((float4*)(out + 1572864))[idx] = sv;   // soft_slots
    ((float4*)(out + 1835008))[idx] = sv;   // expert_inputs (same data)

    ((float4*)out)[idx] = make_float4(0.125f, 0.125f, 0.125f, 0.125f);

    float base = (float)((idx * 4) & 7);    // 0 or 4
    ((float4*)(out + 262144))[idx] = make_float4(base, base + 1.f, base + 2.f, base + 3.f);
}

extern "C" void kernel_launch(void* const* d_in, const int* in_sizes, int n_in,
                              void* d_out, int out_size, void* d_ws, size_t ws_size,
                              hipStream_t stream) {
    const float* x    = (const float*)d_in[0];
    const float* phi  = (const float*)d_in[1];
    const float* bias = (const float*)d_in[2];
    float* out = (float*)d_out;

    // workspace: logits (4 MiB = 1048576 f) + partials (8 MiB = 2097152 f)
    float* logits = (float*)d_ws;
    float* part   = logits + (size_t)B * S * KK;

    float* pw_out = out + 524288;  // phi_weights region of d_out

    k1_logits<<<dim3(B * S / 64), dim3(256), 0, stream>>>(x, phi, bias, logits);
    k2_softmax<<<dim3(B * KK), dim3(256), 0, stream>>>(logits, pw_out);
    k3_partial<<<dim3(256), dim3(256), 0, stream>>>(x, pw_out, part);
    k4_finalize<<<dim3(256), dim3(256), 0, stream>>>(part, out);
}

// Round 2
// 269.424 us; speedup vs baseline: 1.4966x; 1.4966x over previous
//
#include <hip/hip_runtime.h>
#include <hip/hip_bf16.h>

// SoftMoEGating: B=8, S=4096, D=1024, E=8, P=4, K=E*P=32
#define B 8
#define S 4096
#define DD 1024
#define KK 32

// ---------------------------------------------------------------------------
// K1: partial logits over a D-slice, written K-MAJOR: lp[dq][b][k][s].
// grid = B * 32 s-tiles * DSPLIT. block 256 (4 waves). Wave owns 8 k (kg),
// lane owns tokens {lane, lane+64} of a 128-token tile. x tile staged in LDS
// (stride 36 floats: b128 reads & writes are 2-way = free). phi read via
// wave-uniform addresses (-> s_load), 64 FMAs per 4-d group.
// ---------------------------------------------------------------------------
template <int DSPLIT>
__global__ __launch_bounds__(256) void k1_logits(const float* __restrict__ x,
                                                 const float* __restrict__ phi,
                                                 float* __restrict__ lp) {
    constexpr int DCH = DD / DSPLIT;   // 256 (or 512 fallback)
    constexpr int NCH = DCH / 32;      // chunks of 32 d
    __shared__ float xt[128 * 36];

    const int bid = blockIdx.x;
    const int dq  = bid & (DSPLIT - 1);
    const int st  = (bid / DSPLIT) & 31;
    const int b   = bid / (DSPLIT * 32);
    const int s0  = st * 128;
    const int tid = threadIdx.x;
    const int kg  = __builtin_amdgcn_readfirstlane(tid >> 6);
    const int lane = tid & 63;

    float acc0[8], acc1[8];
#pragma unroll
    for (int j = 0; j < 8; ++j) { acc0[j] = 0.f; acc1[j] = 0.f; }

    const float* xb = x + ((size_t)(b * S + s0)) * DD + dq * DCH;

    for (int ch = 0; ch < NCH; ++ch) {
        __syncthreads();
        // stage 128 tokens x 32 d, coalesced float4
#pragma unroll
        for (int i = 0; i < 4; ++i) {
            int f = tid + i * 256;
            int row = f >> 3;
            int c4 = f & 7;
            float4 v = *(const float4*)(xb + (size_t)row * DD + ch * 32 + c4 * 4);
            *(float4*)(xt + row * 36 + c4 * 4) = v;
        }
        __syncthreads();

        const float* pbase = phi + (size_t)(dq * DCH + ch * 32) * KK + kg * 8;
#pragma unroll
        for (int g = 0; g < 8; ++g) {
            float4 a0 = *(const float4*)(xt + lane * 36 + g * 4);
            float4 a1 = *(const float4*)(xt + (lane + 64) * 36 + g * 4);
            const float* a0p = &a0.x;
            const float* a1p = &a1.x;
#pragma unroll
            for (int dd = 0; dd < 4; ++dd) {
                const float* pr = pbase + (size_t)(g * 4 + dd) * KK;  // uniform
                float4 pA = *(const float4*)(pr);
                float4 pB = *(const float4*)(pr + 4);
                float av0 = a0p[dd];
                float av1 = a1p[dd];
                acc0[0] += av0 * pA.x; acc0[1] += av0 * pA.y;
                acc0[2] += av0 * pA.z; acc0[3] += av0 * pA.w;
                acc0[4] += av0 * pB.x; acc0[5] += av0 * pB.y;
                acc0[6] += av0 * pB.z; acc0[7] += av0 * pB.w;
                acc1[0] += av1 * pA.x; acc1[1] += av1 * pA.y;
                acc1[2] += av1 * pA.z; acc1[3] += av1 * pA.w;
                acc1[4] += av1 * pB.x; acc1[5] += av1 * pB.y;
                acc1[6] += av1 * pB.z; acc1[7] += av1 * pB.w;
            }
        }
    }

    // lp[dq][b][k][s], coalesced dword stores (lanes = consecutive s)
    float* o = lp + (((size_t)dq * B + b) * KK + kg * 8) * S + s0;
#pragma unroll
    for (int j = 0; j < 8; ++j) {
        o[(size_t)j * S + lane]      = acc0[j];
        o[(size_t)j * S + 64 + lane] = acc1[j];
    }
}

// ---------------------------------------------------------------------------
// K2: sum DSPLIT partials + bias, softmax over S per (b,k), write phi_weights
// into d_out ([b][s][k] layout; writes uncoalesced but L2-absorbed, 4 MB).
// grid 256 = B*KK, block 256, 16 elements/thread in registers.
// ---------------------------------------------------------------------------
template <int DSPLIT>
__global__ __launch_bounds__(256) void k2_softmax(const float* __restrict__ lp,
                                                  const float* __restrict__ bias,
                                                  float* __restrict__ pw) {
    const int b = blockIdx.x >> 5;
    const int k = blockIdx.x & 31;
    const int tid = threadIdx.x;
    const int wave = tid >> 6, lane = tid & 63;
    const size_t base = ((size_t)b * KK + k) * S;
    const float bk = bias[k];

    float v[16];
    float m = -1e30f;
#pragma unroll
    for (int i = 0; i < 16; ++i) {
        int s = tid + i * 256;
        float t = bk;
#pragma unroll
        for (int p = 0; p < DSPLIT; ++p) t += lp[(size_t)p * (B * KK * S) + base + s];
        v[i] = t;
        m = fmaxf(m, t);
    }
#pragma unroll
    for (int off = 32; off >= 1; off >>= 1) m = fmaxf(m, __shfl_xor(m, off, 64));

    __shared__ float redm[4];
    __shared__ float reds[4];
    if (lane == 0) redm[wave] = m;
    __syncthreads();
    m = fmaxf(fmaxf(redm[0], redm[1]), fmaxf(redm[2], redm[3]));

    float ssum = 0.f;
#pragma unroll
    for (int i = 0; i < 16; ++i) {
        v[i] = __expf(v[i] - m);
        ssum += v[i];
    }
#pragma unroll
    for (int off = 32; off >= 1; off >>= 1) ssum += __shfl_xor(ssum, off, 64);
    if (lane == 0) reds[wave] = ssum;
    __syncthreads();
    ssum = reds[0] + reds[1] + reds[2] + reds[3];

    float r = 1.0f / ssum;
#pragma unroll
    for (int i = 0; i < 16; ++i) {
        int s = tid + i * 256;
        pw[((size_t)b * S + s) * KK + k] = v[i] * r;
    }
}

// ---------------------------------------------------------------------------
// K3: partial soft_slots, NO LDS: x[s][dt*256+lane*4] float4 loads are already
// coalesced; w loads wave-uniform (8 consecutive floats -> s_load_dwordx8).
// grid = B * 4 dtiles * SSPLIT. 8 float4 accumulators/thread (kg x lane-d).
// part[sc][b][k][d] aliases K1's lp region (dead after K2).
// ---------------------------------------------------------------------------
template <int SSPLIT>
__global__ __launch_bounds__(256) void k3_partial(const float* __restrict__ x,
                                                  const float* __restrict__ pw,
                                                  float* __restrict__ part) {
    constexpr int SCH = S / SSPLIT;  // 256 (or 512 fallback)
    const int bid = blockIdx.x;
    const int sc = bid % SSPLIT;
    const int dt = (bid / SSPLIT) & 3;
    const int b  = bid / (SSPLIT * 4);
    const int tid = threadIdx.x;
    const int kg = __builtin_amdgcn_readfirstlane(tid >> 6);
    const int lane = tid & 63;

    float4 acc[8];
#pragma unroll
    for (int j = 0; j < 8; ++j) acc[j] = make_float4(0.f, 0.f, 0.f, 0.f);

    const float* xb = x + ((size_t)(b * S + sc * SCH)) * DD + dt * 256 + lane * 4;
    const float* wb = pw + ((size_t)(b * S + sc * SCH)) * KK + kg * 8;

#pragma unroll 4
    for (int s = 0; s < SCH; ++s) {
        float4 xv = *(const float4*)(xb + (size_t)s * DD);
        const float* wr = wb + (size_t)s * KK;  // uniform
        float4 wA = *(const float4*)(wr);
        float4 wB = *(const float4*)(wr + 4);
        acc[0].x += wA.x * xv.x; acc[0].y += wA.x * xv.y; acc[0].z += wA.x * xv.z; acc[0].w += wA.x * xv.w;
        acc[1].x += wA.y * xv.x; acc[1].y += wA.y * xv.y; acc[1].z += wA.y * xv.z; acc[1].w += wA.y * xv.w;
        acc[2].x += wA.z * xv.x; acc[2].y += wA.z * xv.y; acc[2].z += wA.z * xv.z; acc[2].w += wA.z * xv.w;
        acc[3].x += wA.w * xv.x; acc[3].y += wA.w * xv.y; acc[3].z += wA.w * xv.z; acc[3].w += wA.w * xv.w;
        acc[4].x += wB.x * xv.x; acc[4].y += wB.x * xv.y; acc[4].z += wB.x * xv.z; acc[4].w += wB.x * xv.w;
        acc[5].x += wB.y * xv.x; acc[5].y += wB.y * xv.y; acc[5].z += wB.y * xv.z; acc[5].w += wB.y * xv.w;
        acc[6].x += wB.z * xv.x; acc[6].y += wB.z * xv.y; acc[6].z += wB.z * xv.z; acc[6].w += wB.z * xv.w;
        acc[7].x += wB.w * xv.x; acc[7].y += wB.w * xv.y; acc[7].z += wB.w * xv.z; acc[7].w += wB.w * xv.w;
    }

    float* pp = part + (((size_t)sc * B + b) * KK + kg * 8) * DD + dt * 256 + lane * 4;
#pragma unroll
    for (int j = 0; j < 8; ++j) *(float4*)(pp + (size_t)j * DD) = acc[j];
}

// ---------------------------------------------------------------------------
// K4: reduce SSPLIT partials -> soft_slots + expert_inputs; fill
// expert_weights (0.125) and expert_indices (0..7 as float).
// grid 256, block 256, one float4 lane-slot each (65536 total).
// ---------------------------------------------------------------------------
template <int SSPLIT>
__global__ __launch_bounds__(256) void k4_finalize(const float* __restrict__ part,
                                                   float* __restrict__ out) {
    const int idx = blockIdx.x * 256 + threadIdx.x;  // 0..65535 float4 slots
    const float4* p4 = (const float4*)part;

    float4 sv = p4[idx];
#pragma unroll
    for (int c = 1; c < SSPLIT; ++c) {
        float4 t = p4[(size_t)c * 65536 + idx];
        sv.x += t.x; sv.y += t.y; sv.z += t.z; sv.w += t.w;
    }

    // out floats: ew[0..262144) ei[262144..524288) pw[524288..1572864)
    //             ss[1572864..1835008) einp[1835008..2097152)
    ((float4*)(out + 1572864))[idx] = sv;   // soft_slots
    ((float4*)(out + 1835008))[idx] = sv;   // expert_inputs

    ((float4*)out)[idx] = make_float4(0.125f, 0.125f, 0.125f, 0.125f);
    float base = (float)((idx * 4) & 7);
    ((float4*)(out + 262144))[idx] = make_float4(base, base + 1.f, base + 2.f, base + 3.f);
}

extern "C" void kernel_launch(void* const* d_in, const int* in_sizes, int n_in,
                              void* d_out, int out_size, void* d_ws, size_t ws_size,
                              hipStream_t stream) {
    const float* x    = (const float*)d_in[0];
    const float* phi  = (const float*)d_in[1];
    const float* bias = (const float*)d_in[2];
    float* out = (float*)d_out;

    float* lp   = (float*)d_ws;   // logit partials; K3 partials ALIAS this
    float* part = (float*)d_ws;   // (dead after K2 in stream order)
    float* pw   = out + 524288;   // phi_weights region of d_out

    if (ws_size >= (size_t)17 * 1024 * 1024) {
        // big config: K1 d-split 4 (16 MB), K3 s-split 16 (16 MB, aliased)
        k1_logits<4><<<dim3(B * 32 * 4), dim3(256), 0, stream>>>(x, phi, lp);
        k2_softmax<4><<<dim3(B * KK), dim3(256), 0, stream>>>(lp, bias, pw);
        k3_partial<16><<<dim3(B * 4 * 16), dim3(256), 0, stream>>>(x, pw, part);
        k4_finalize<16><<<dim3(256), dim3(256), 0, stream>>>(part, out);
    } else {
        // fallback: K1 d-split 2 (8 MB), K3 s-split 8 (8 MB, aliased)
        k1_logits<2><<<dim3(B * 32 * 2), dim3(256), 0, stream>>>(x, phi, lp);
        k2_softmax<2><<<dim3(B * KK), dim3(256), 0, stream>>>(lp, bias, pw);
        k3_partial<8><<<dim3(B * 4 * 8), dim3(256), 0, stream>>>(x, pw, part);
        k4_finalize<8><<<dim3(256), dim3(256), 0, stream>>>(part, out);
    }
}

// Round 3
// 267.877 us; speedup vs baseline: 1.5053x; 1.0058x over previous
//
#include <hip/hip_runtime.h>
#include <hip/hip_bf16.h>

// SoftMoEGating: B=8, S=4096, D=1024, E=8, P=4, K=E*P=32
#define B 8
#define S 4096
#define DD 1024
#define KK 32

// ---------------------------------------------------------------------------
// K1: partial logits over a D-slice (DSPLIT=2), K-MAJOR out: lp[dq][b][k][s].
// grid = B*64*2 = 1024 (4 blocks/CU). Block: 64 tokens x 512 d. Double-buffered
// LDS (chunks of 32 d) with register prefetch: next chunk's global loads are in
// flight during the 256-FMA compute block. Wave owns 8 k; lane owns 1 token.
// bias folded in at dq==0.
// ---------------------------------------------------------------------------
__global__ __launch_bounds__(256) void k1_logits(const float* __restrict__ x,
                                                 const float* __restrict__ phi,
                                                 const float* __restrict__ bias,
                                                 float* __restrict__ lp) {
    constexpr int DCH = 512, NCH = 16;
    __shared__ float xt[2][64 * 36];

    const int bid = blockIdx.x;
    const int dq  = bid & 1;
    const int st  = (bid >> 1) & 63;
    const int b   = bid >> 7;
    const int s0  = st * 64;
    const int tid = threadIdx.x;
    const int kg  = __builtin_amdgcn_readfirstlane(tid >> 6);
    const int lane = tid & 63;

    float acc[8];
#pragma unroll
    for (int j = 0; j < 8; ++j) acc[j] = (dq == 0) ? bias[kg * 8 + j] : 0.f;

    const float* xb = x + ((size_t)(b * S + s0)) * DD + dq * DCH;
    const int row = tid >> 3;      // 0..31
    const int c4  = tid & 7;       // 0..7

    // stage chunk 0
    {
        float4 p0 = *(const float4*)(xb + (size_t)row * DD + c4 * 4);
        float4 p1 = *(const float4*)(xb + (size_t)(row + 32) * DD + c4 * 4);
        *(float4*)(&xt[0][row * 36 + c4 * 4]) = p0;
        *(float4*)(&xt[0][(row + 32) * 36 + c4 * 4]) = p1;
    }
    __syncthreads();

    for (int ch = 0; ch < NCH; ++ch) {
        const int cur = ch & 1;
        float4 q0, q1;
        if (ch + 1 < NCH) {   // issue prefetch; waited only at the LDS write
            q0 = *(const float4*)(xb + (size_t)row * DD + (ch + 1) * 32 + c4 * 4);
            q1 = *(const float4*)(xb + (size_t)(row + 32) * DD + (ch + 1) * 32 + c4 * 4);
        }

        const float* pbase = phi + (size_t)(dq * DCH + ch * 32) * KK + kg * 8;
        const float* xrow  = &xt[cur][lane * 36];
#pragma unroll
        for (int g = 0; g < 8; ++g) {
            float4 a = *(const float4*)(xrow + g * 4);
            const float* ap = &a.x;
#pragma unroll
            for (int dd = 0; dd < 4; ++dd) {
                const float* pr = pbase + (size_t)(g * 4 + dd) * KK;  // uniform
                float4 pA = *(const float4*)pr;
                float4 pB = *(const float4*)(pr + 4);
                float av = ap[dd];
                acc[0] += av * pA.x; acc[1] += av * pA.y;
                acc[2] += av * pA.z; acc[3] += av * pA.w;
                acc[4] += av * pB.x; acc[5] += av * pB.y;
                acc[6] += av * pB.z; acc[7] += av * pB.w;
            }
        }
        __syncthreads();
        if (ch + 1 < NCH) {
            *(float4*)(&xt[cur ^ 1][row * 36 + c4 * 4]) = q0;
            *(float4*)(&xt[cur ^ 1][(row + 32) * 36 + c4 * 4]) = q1;
        }
        __syncthreads();
    }

    float* o = lp + (((size_t)dq * B + b) * KK + kg * 8) * S + s0;
#pragma unroll
    for (int j = 0; j < 8; ++j) o[(size_t)j * S + lane] = acc[j];
}

// ---------------------------------------------------------------------------
// K2a: per (b,k, s-chunk of 512): partial max M and partial sum L of exp(v-M).
// grid = B*KK*8 = 2048. Reads both lp d-parts (bias already folded in).
// ---------------------------------------------------------------------------
__global__ __launch_bounds__(256) void k2a_partial(const float* __restrict__ lp,
                                                   float* __restrict__ pmax,
                                                   float* __restrict__ psum) {
    const int bid = blockIdx.x;
    const int c  = bid & 7;
    const int bk = bid >> 3;
    const int tid = threadIdx.x;
    const int wave = tid >> 6, lane = tid & 63;
    const size_t base = (size_t)bk * S + c * 512;

    float v0 = lp[base + tid]       + lp[1048576 + base + tid];
    float v1 = lp[base + tid + 256] + lp[1048576 + base + tid + 256];

    float m = fmaxf(v0, v1);
#pragma unroll
    for (int off = 32; off >= 1; off >>= 1) m = fmaxf(m, __shfl_xor(m, off, 64));
    __shared__ float sm[4], sl[4];
    if (lane == 0) sm[wave] = m;
    __syncthreads();
    const float M = fmaxf(fmaxf(sm[0], sm[1]), fmaxf(sm[2], sm[3]));

    float l = __expf(v0 - M) + __expf(v1 - M);
#pragma unroll
    for (int off = 32; off >= 1; off >>= 1) l += __shfl_xor(l, off, 64);
    if (lane == 0) sl[wave] = l;
    __syncthreads();
    if (tid == 0) {
        pmax[bid] = M;
        psum[bid] = sl[0] + sl[1] + sl[2] + sl[3];
    }
}

// ---------------------------------------------------------------------------
// K2c: combine partials -> (M,1/L) per k; normalize; write pwT[b][k][s]
// (coalesced, for K3) AND d_out's [b][s][k] layout via LDS transpose
// (coalesced float4 stores — no scattered stores anywhere).
// grid = B*32 (s-chunks of 128), block 256.
// ---------------------------------------------------------------------------
__global__ __launch_bounds__(256) void k2c_norm(const float* __restrict__ lp,
                                                const float* __restrict__ pmax,
                                                const float* __restrict__ psum,
                                                float* __restrict__ pwT,
                                                float* __restrict__ pw_out) {
    __shared__ float tile[128][33];
    __shared__ float sM[32], sLinv[32];
    const int b  = blockIdx.x >> 5;
    const int sc = blockIdx.x & 31;
    const int s0 = sc * 128;
    const int tid = threadIdx.x;

    if (tid < 32) {
        const int k = tid;
        float M = -1e30f, L = 0.f;
#pragma unroll
        for (int c = 0; c < 8; ++c) {
            float mc = pmax[(b * KK + k) * 8 + c];
            float lc = psum[(b * KK + k) * 8 + c];
            float nM = fmaxf(M, mc);
            L = L * __expf(M - nM) + lc * __expf(mc - nM);
            M = nM;
        }
        sM[k] = M;
        sLinv[k] = 1.0f / L;
    }
    __syncthreads();

    const int sL = tid & 127;
    const int kh = tid >> 7;   // 0..1
#pragma unroll
    for (int kk = 0; kk < 16; ++kk) {
        const int k = kk * 2 + kh;
        const size_t idx = ((size_t)b * KK + k) * S + s0 + sL;
        float v = lp[idx] + lp[1048576 + idx];
        float w = __expf(v - sM[k]) * sLinv[k];
        pwT[idx] = w;
        tile[sL][k] = w;
    }
    __syncthreads();

    float* ob = pw_out + ((size_t)b * S + s0) * KK;
#pragma unroll
    for (int i = 0; i < 4; ++i) {
        const int idx4 = tid + i * 256;         // 0..1023 float4 slots
        const int sl = idx4 >> 3, kq = idx4 & 7;
        float4 v4 = make_float4(tile[sl][kq * 4 + 0], tile[sl][kq * 4 + 1],
                                tile[sl][kq * 4 + 2], tile[sl][kq * 4 + 3]);
        ((float4*)ob)[idx4] = v4;
    }
}

// ---------------------------------------------------------------------------
// K3: partial soft_slots. grid = B*4*SSPLIT. x float4 loads coalesced (lane=d);
// weights read from k-major pwT as 8 uniform float4 per 4 tokens. 4 independent
// x-loads in flight per thread; x should be L3-resident after K1.
// part[sc][b][k][d] in ws.
// ---------------------------------------------------------------------------
template <int SSPLIT>
__global__ __launch_bounds__(256) void k3_partial(const float* __restrict__ x,
                                                  const float* __restrict__ pwT,
                                                  float* __restrict__ part) {
    constexpr int SCH = S / SSPLIT;
    const int bid = blockIdx.x;
    const int sc = bid % SSPLIT;
    const int dt = (bid / SSPLIT) & 3;
    const int b  = bid / (SSPLIT * 4);
    const int tid = threadIdx.x;
    const int kg = __builtin_amdgcn_readfirstlane(tid >> 6);
    const int lane = tid & 63;

    float4 acc[8];
#pragma unroll
    for (int j = 0; j < 8; ++j) acc[j] = make_float4(0.f, 0.f, 0.f, 0.f);

    const float* xb = x + ((size_t)(b * S + sc * SCH)) * DD + dt * 256 + lane * 4;
    const float* wb = pwT + ((size_t)b * KK + kg * 8) * S + sc * SCH;

    for (int ss = 0; ss < SCH / 4; ++ss) {
        float4 wq[8];
#pragma unroll
        for (int j = 0; j < 8; ++j) wq[j] = *(const float4*)(wb + (size_t)j * S + ss * 4);
#pragma unroll
        for (int dd = 0; dd < 4; ++dd) {
            float4 xv = *(const float4*)(xb + (size_t)(ss * 4 + dd) * DD);
#pragma unroll
            for (int j = 0; j < 8; ++j) {
                float w = ((const float*)&wq[j])[dd];
                acc[j].x += w * xv.x; acc[j].y += w * xv.y;
                acc[j].z += w * xv.z; acc[j].w += w * xv.w;
            }
        }
    }

    float* pp = part + (((size_t)sc * B + b) * KK + kg * 8) * DD + dt * 256 + lane * 4;
#pragma unroll
    for (int j = 0; j < 8; ++j) *(float4*)(pp + (size_t)j * DD) = acc[j];
}

// ---------------------------------------------------------------------------
// K4: reduce SSPLIT partials -> soft_slots + expert_inputs; fill
// expert_weights (0.125) and expert_indices (0..7). grid 256, block 256.
// ---------------------------------------------------------------------------
template <int SSPLIT>
__global__ __launch_bounds__(256) void k4_finalize(const float* __restrict__ part,
                                                   float* __restrict__ out) {
    const int idx = blockIdx.x * 256 + threadIdx.x;  // 0..65535 float4 slots
    const float4* p4 = (const float4*)part;

    float4 sv = p4[idx];
#pragma unroll
    for (int c = 1; c < SSPLIT; ++c) {
        float4 t = p4[(size_t)c * 65536 + idx];
        sv.x += t.x; sv.y += t.y; sv.z += t.z; sv.w += t.w;
    }

    // out floats: ew[0..262144) ei[262144..524288) pw[524288..1572864)
    //             ss[1572864..1835008) einp[1835008..2097152)
    ((float4*)(out + 1572864))[idx] = sv;
    ((float4*)(out + 1835008))[idx] = sv;
    ((float4*)out)[idx] = make_float4(0.125f, 0.125f, 0.125f, 0.125f);
    float base = (float)((idx * 4) & 7);
    ((float4*)(out + 262144))[idx] = make_float4(base, base + 1.f, base + 2.f, base + 3.f);
}

extern "C" void kernel_launch(void* const* d_in, const int* in_sizes, int n_in,
                              void* d_out, int out_size, void* d_ws, size_t ws_size,
                              hipStream_t stream) {
    const float* x    = (const float*)d_in[0];
    const float* phi  = (const float*)d_in[1];
    const float* bias = (const float*)d_in[2];
    float* out = (float*)d_out;

    // ws layout (floats):
    //   lp    @ 0         (2 * 1048576 = 8 MB, two d-parts)
    //   pmax  @ 2097152   (2048)
    //   psum  @ 2101248   (2048)
    //   pwT   @ 2105344   (1048576, k-major weights)
    //   part  @ 3153920   (SSPLIT * 262144)
    float* lp   = (float*)d_ws;
    float* pmax = lp + 2097152;
    float* psum = lp + 2101248;
    float* pwT  = lp + 2105344;
    float* part = lp + 3153920;
    float* pw_out = out + 524288;

    k1_logits<<<dim3(1024), dim3(256), 0, stream>>>(x, phi, bias, lp);
    k2a_partial<<<dim3(2048), dim3(256), 0, stream>>>(lp, pmax, psum);
    k2c_norm<<<dim3(256), dim3(256), 0, stream>>>(lp, pmax, psum, pwT, pw_out);

    if (ws_size >= (size_t)47 * 1024 * 1024) {
        k3_partial<32><<<dim3(B * 4 * 32), dim3(256), 0, stream>>>(x, pwT, part);
        k4_finalize<32><<<dim3(256), dim3(256), 0, stream>>>(part, out);
    } else {
        k3_partial<8><<<dim3(B * 4 * 8), dim3(256), 0, stream>>>(x, pwT, part);
        k4_finalize<8><<<dim3(256), dim3(256), 0, stream>>>(part, out);
    }
}

// Round 5
// 234.009 us; speedup vs baseline: 1.7231x; 1.1447x over previous
//
#include <hip/hip_runtime.h>
#include <hip/hip_bf16.h>

// SoftMoEGating: B=8, S=4096, D=1024, E=8, P=4, K=E*P=32
#define B 8
#define S 4096
#define DD 1024
#define KK 32

typedef __attribute__((ext_vector_type(8))) short bf16x8;
typedef __attribute__((ext_vector_type(16))) float f32x16;

static __device__ __forceinline__ unsigned short f2bf(float f) {
    unsigned int u = __builtin_bit_cast(unsigned int, f);
    u += 0x7FFFu + ((u >> 16) & 1u);     // RNE
    return (unsigned short)(u >> 16);
}

// ---------------------------------------------------------------------------
// K0: phi [1024 d][32 k] fp32  ->  phiT [32 k][1024 d] bf16 (B-operand layout).
// grid 32 (32 d-rows each), LDS transpose, tiny.
// ---------------------------------------------------------------------------
__global__ __launch_bounds__(256) void k0_phit(const float* __restrict__ phi,
                                               unsigned short* __restrict__ phiT) {
    __shared__ float lt[32][33];
    const int d0 = blockIdx.x * 32;
    const int tid = threadIdx.x;
#pragma unroll
    for (int i = 0; i < 4; ++i) {
        int slot = tid + i * 256;
        int d = slot >> 5, k = slot & 31;
        lt[d][k] = phi[(size_t)(d0 + d) * KK + k];
    }
    __syncthreads();
    const int k = tid >> 3, c = tid & 7, d = c * 4;
    short4 pk;
    pk.x = (short)f2bf(lt[d + 0][k]);
    pk.y = (short)f2bf(lt[d + 1][k]);
    pk.z = (short)f2bf(lt[d + 2][k]);
    pk.w = (short)f2bf(lt[d + 3][k]);
    *(short4*)(phiT + (size_t)k * DD + d0 + d) = pk;
}

// ---------------------------------------------------------------------------
// K1: logits via MFMA 32x32x16 bf16. grid = 8b x 32 stile(128 s) x 2 dq = 512.
// Block: 4 waves; wave w owns tokens [w*32,w*32+32) x all 32 k, K-dim = 512 d.
// LDS: phiT slice [32 k][512 d] bf16 (32 KB, staged once) + x dbuf
// 2 x [128 s][64 d] bf16 (16 KB each), XOR-swizzled 16B blocks (conflict-free
// b128 frags). Register-prefetch staging (fp32 -> bf16 cvt in regs).
// Epilogue transposes C through LDS -> coalesced k-major stores
// lp[dq][b][k][s]. Bias folded into acc init at dq==0.
// ---------------------------------------------------------------------------
__global__ __launch_bounds__(256) void k1_logits(const float* __restrict__ x,
                                                 const unsigned short* __restrict__ phiT,
                                                 const float* __restrict__ bias,
                                                 float* __restrict__ lp) {
    __shared__ __align__(16) char sm[32768 + 2 * 16384];

    const int bid = blockIdx.x;
    const int dq = bid & 1;
    const int st = (bid >> 1) & 31;
    const int b  = bid >> 6;
    const int s0 = st * 128;
    const int tid = threadIdx.x;
    const int wv = __builtin_amdgcn_readfirstlane(tid >> 6);
    const int lane = tid & 63;
    const int l31 = lane & 31;
    const int half = lane >> 5;

    // stage phiT slice (32 KB) as uint4, swizzled
    {
        const uint4* pg = (const uint4*)phiT;   // row = 128 uint4
#pragma unroll
        for (int i = 0; i < 8; ++i) {
            int slot = tid + i * 256;
            int k = slot >> 6, blk = slot & 63;
            uint4 v = pg[(size_t)k * 128 + dq * 64 + blk];
            *(uint4*)(sm + (size_t)k * 1024 + ((blk ^ (k & 7)) << 4)) = v;
        }
    }

    f32x16 acc;
    {
        float bv = (dq == 0) ? bias[l31] : 0.f;
#pragma unroll
        for (int r = 0; r < 16; ++r) acc[r] = bv;
    }

    const float* xg = x + ((size_t)(b * S + s0)) * DD + dq * 512;

    float4 q[8];
    auto load8 = [&](int ch) {
#pragma unroll
        for (int i = 0; i < 8; ++i) {
            int slot = tid + i * 256;
            int s = slot >> 4, c4 = slot & 15;
            q[i] = *(const float4*)(xg + (size_t)s * DD + ch * 64 + c4 * 4);
        }
    };
    auto store8 = [&](char* buf) {
#pragma unroll
        for (int i = 0; i < 8; ++i) {
            int slot = tid + i * 256;
            int s = slot >> 4, c4 = slot & 15;
            short4 pk;
            pk.x = (short)f2bf(q[i].x);
            pk.y = (short)f2bf(q[i].y);
            pk.z = (short)f2bf(q[i].z);
            pk.w = (short)f2bf(q[i].w);
            *(short4*)(buf + (size_t)s * 128 + (((c4 >> 1) ^ (s & 7)) << 4) + (c4 & 1) * 8) = pk;
        }
    };

    load8(0);
    store8(sm + 32768);
    __syncthreads();

    const int srow = wv * 32 + l31;
    const int sx = srow & 7;
    const int kx = l31 & 7;

    for (int ch = 0; ch < 8; ++ch) {
        char* cur = sm + 32768 + (ch & 1) * 16384;
        char* nxt = sm + 32768 + ((ch & 1) ^ 1) * 16384;
        if (ch < 7) load8(ch + 1);
#pragma unroll
        for (int step = 0; step < 4; ++step) {
            int blk = step * 2 + half;
            bf16x8 af  = *(const bf16x8*)(cur + (size_t)srow * 128 + ((blk ^ sx) << 4));
            bf16x8 bfv = *(const bf16x8*)(sm + (size_t)l31 * 1024 + (((ch * 8 + blk) ^ kx) << 4));
            acc = __builtin_amdgcn_mfma_f32_32x32x16_bf16(af, bfv, acc, 0, 0, 0);
        }
        __syncthreads();
        if (ch < 7) store8(nxt);
        __syncthreads();
    }

    // epilogue: C (col=k, row pattern) -> LDS [32 k][128 s] -> coalesced store
    float* lt = (float*)(sm + 32768);   // 32*129 fp32 = 16.5 KB (x bufs dead)
#pragma unroll
    for (int r = 0; r < 16; ++r) {
        int row = (r & 3) + 8 * (r >> 2) + 4 * half;   // token row within 32
        lt[(size_t)l31 * 129 + wv * 32 + row] = acc[r];
    }
    __syncthreads();
    float* o = lp + ((size_t)(dq * B + b) * KK) * S + s0;
#pragma unroll
    for (int i = 0; i < 4; ++i) {
        int slot = tid + i * 256;
        int k = slot >> 5, s4 = slot & 31;
        float4 v;
        v.x = lt[k * 129 + s4 * 4 + 0];
        v.y = lt[k * 129 + s4 * 4 + 1];
        v.z = lt[k * 129 + s4 * 4 + 2];
        v.w = lt[k * 129 + s4 * 4 + 3];
        *(float4*)(o + (size_t)k * S + s4 * 4) = v;
    }
}

// ---------------------------------------------------------------------------
// K2a: per (b,k, s-chunk 512): partial max + sum of exp. grid 2048.
// ---------------------------------------------------------------------------
__global__ __launch_bounds__(256) void k2a_partial(const float* __restrict__ lp,
                                                   float* __restrict__ pmax,
                                                   float* __restrict__ psum) {
    const int bid = blockIdx.x;
    const int c  = bid & 7;
    const int bk = bid >> 3;
    const int tid = threadIdx.x;
    const int wave = tid >> 6, lane = tid & 63;
    const size_t base = (size_t)bk * S + c * 512;

    float v0 = lp[base + tid]       + lp[1048576 + base + tid];
    float v1 = lp[base + tid + 256] + lp[1048576 + base + tid + 256];

    float m = fmaxf(v0, v1);
#pragma unroll
    for (int off = 32; off >= 1; off >>= 1) m = fmaxf(m, __shfl_xor(m, off, 64));
    __shared__ float sm_[4], sl[4];
    if (lane == 0) sm_[wave] = m;
    __syncthreads();
    const float M = fmaxf(fmaxf(sm_[0], sm_[1]), fmaxf(sm_[2], sm_[3]));

    float l = __expf(v0 - M) + __expf(v1 - M);
#pragma unroll
    for (int off = 32; off >= 1; off >>= 1) l += __shfl_xor(l, off, 64);
    if (lane == 0) sl[wave] = l;
    __syncthreads();
    if (tid == 0) {
        pmax[bid] = M;
        psum[bid] = sl[0] + sl[1] + sl[2] + sl[3];
    }
}

// ---------------------------------------------------------------------------
// K2c: combine partials, normalize; write wbT bf16 [b][k][s] (coalesced, for
// K3's A-operand) AND d_out's [b][s][k] fp32 layout via LDS transpose.
// grid = B*32 (s-chunks of 128).
// ---------------------------------------------------------------------------
__global__ __launch_bounds__(256) void k2c_norm(const float* __restrict__ lp,
                                                const float* __restrict__ pmax,
                                                const float* __restrict__ psum,
                                                unsigned short* __restrict__ wbT,
                                                float* __restrict__ pw_out) {
    __shared__ float tile[128][33];
    __shared__ float sM[32], sLinv[32];
    const int b  = blockIdx.x >> 5;
    const int sc = blockIdx.x & 31;
    const int s0 = sc * 128;
    const int tid = threadIdx.x;

    if (tid < 32) {
        const int k = tid;
        float M = -1e30f, L = 0.f;
#pragma unroll
        for (int c = 0; c < 8; ++c) {
            float mc = pmax[(b * KK + k) * 8 + c];
            float lc = psum[(b * KK + k) * 8 + c];
            float nM = fmaxf(M, mc);
            L = L * __expf(M - nM) + lc * __expf(mc - nM);
            M = nM;
        }
        sM[k] = M;
        sLinv[k] = 1.0f / L;
    }
    __syncthreads();

    const int sL = tid & 127;
    const int kh = tid >> 7;
#pragma unroll
    for (int kk = 0; kk < 16; ++kk) {
        const int k = kk * 2 + kh;
        const size_t idx = ((size_t)b * KK + k) * S + s0 + sL;
        float v = lp[idx] + lp[1048576 + idx];
        float w = __expf(v - sM[k]) * sLinv[k];
        wbT[idx] = f2bf(w);
        tile[sL][k] = w;
    }
    __syncthreads();

    float* ob = pw_out + ((size_t)b * S + s0) * KK;
#pragma unroll
    for (int i = 0; i < 4; ++i) {
        const int idx4 = tid + i * 256;
        const int sl = idx4 >> 3, kq = idx4 & 7;
        float4 v4 = make_float4(tile[sl][kq * 4 + 0], tile[sl][kq * 4 + 1],
                                tile[sl][kq * 4 + 2], tile[sl][kq * 4 + 3]);
        ((float4*)ob)[idx4] = v4;
    }
}

// ---------------------------------------------------------------------------
// K3: soft_slots via MFMA 32x32x16 bf16: C[k_moe][d] = sum_s w[k][s] x[s][d].
// grid = 8b x 8 dgroup(128 d) x 8 sc(512 s) = 512. Wave w owns d-sub of 32.
// LDS: xT dbuf [128 d][64 s] bf16 (transposed during staging: scalar-d
// coalesced fp32 loads, s-pair packed u32 writes) + wT dbuf [32 k][64 s].
// XOR-swizzled, b128 frag reads. part[sc][b][k][d] fp32.
// ---------------------------------------------------------------------------
__global__ __launch_bounds__(256) void k3_slots(const float* __restrict__ x,
                                                const unsigned int* __restrict__ wbT32,
                                                float* __restrict__ part) {
    __shared__ __align__(16) char sm[2 * 16384 + 2 * 4096];

    const int bid = blockIdx.x;
    const int sc = bid & 7;
    const int dg = (bid >> 3) & 7;
    const int b  = bid >> 6;
    const int tid = threadIdx.x;
    const int wv = __builtin_amdgcn_readfirstlane(tid >> 6);
    const int lane = tid & 63;
    const int l31 = lane & 31;
    const int half = lane >> 5;

    const int dth = tid & 127;      // staging: d lane
    const int sh  = tid >> 7;       // staging: s-half

    const float* xg = x + ((size_t)(b * S + sc * 512)) * DD + dg * 128 + dth;
    const unsigned int* wg = wbT32 + (size_t)b * KK * (S / 2) + sc * 256;

    float q0[16], q1[16];
    unsigned int qw[4];
    auto loadc = [&](int ch) {
#pragma unroll
        for (int j = 0; j < 16; ++j) {
            int sp = sh * 16 + j;
            q0[j] = xg[(size_t)(ch * 64 + sp * 2) * DD];
            q1[j] = xg[(size_t)(ch * 64 + sp * 2 + 1) * DD];
        }
#pragma unroll
        for (int i = 0; i < 4; ++i) {
            int slot = tid + i * 256;
            int k = slot >> 5, c = slot & 31;
            qw[i] = wg[(size_t)k * (S / 2) + ch * 32 + c];
        }
    };
    auto storec = [&](char* xB, char* wB) {
#pragma unroll
        for (int j = 0; j < 16; ++j) {
            int sp = sh * 16 + j;
            unsigned int pkd = (unsigned int)f2bf(q0[j]) | ((unsigned int)f2bf(q1[j]) << 16);
            *(unsigned int*)(xB + (size_t)dth * 128 + (((sp >> 2) ^ (dth & 7)) << 4) + (sp & 3) * 4) = pkd;
        }
#pragma unroll
        for (int i = 0; i < 4; ++i) {
            int slot = tid + i * 256;
            int k = slot >> 5, c = slot & 31;
            *(unsigned int*)(wB + (size_t)k * 128 + (((c >> 2) ^ (k & 7)) << 4) + (c & 3) * 4) = qw[i];
        }
    };

    f32x16 acc;
#pragma unroll
    for (int r = 0; r < 16; ++r) acc[r] = 0.f;

    loadc(0);
    storec(sm, sm + 32768);
    __syncthreads();

    const int dloc = wv * 32 + l31;
    const int dx = dloc & 7;
    const int kx = l31 & 7;

    for (int ch = 0; ch < 8; ++ch) {
        const int cur = ch & 1;
        char* xCur = sm + cur * 16384;
        char* wCur = sm + 32768 + cur * 4096;
        char* xNxt = sm + (cur ^ 1) * 16384;
        char* wNxt = sm + 32768 + (cur ^ 1) * 4096;
        if (ch < 7) loadc(ch + 1);
#pragma unroll
        for (int step = 0; step < 4; ++step) {
            int blk = step * 2 + half;
            bf16x8 af  = *(const bf16x8*)(wCur + (size_t)l31 * 128 + ((blk ^ kx) << 4));
            bf16x8 bfv = *(const bf16x8*)(xCur + (size_t)dloc * 128 + ((blk ^ dx) << 4));
            acc = __builtin_amdgcn_mfma_f32_32x32x16_bf16(af, bfv, acc, 0, 0, 0);
        }
        __syncthreads();
        if (ch < 7) storec(xNxt, wNxt);
        __syncthreads();
    }

    float* pp = part + (((size_t)sc * B + b) * KK) * DD + dg * 128 + wv * 32 + l31;
#pragma unroll
    for (int r = 0; r < 16; ++r) {
        int k = (r & 3) + 8 * (r >> 2) + 4 * half;
        pp[(size_t)k * DD] = acc[r];
    }
}

// ---------------------------------------------------------------------------
// K4: reduce 8 partials -> soft_slots + expert_inputs; fill expert_weights
// (0.125) and expert_indices (0..7). grid 256.
// ---------------------------------------------------------------------------
__global__ __launch_bounds__(256) void k4_finalize(const float* __restrict__ part,
                                                   float* __restrict__ out) {
    const int idx = blockIdx.x * 256 + threadIdx.x;
    const float4* p4 = (const float4*)part;

    float4 sv = p4[idx];
#pragma unroll
    for (int c = 1; c < 8; ++c) {
        float4 t = p4[(size_t)c * 65536 + idx];
        sv.x += t.x; sv.y += t.y; sv.z += t.z; sv.w += t.w;
    }

    // out floats: ew[0..262144) ei[262144..524288) pw[524288..1572864)
    //             ss[1572864..1835008) einp[1835008..2097152)
    ((float4*)(out + 1572864))[idx] = sv;
    ((float4*)(out + 1835008))[idx] = sv;
    ((float4*)out)[idx] = make_float4(0.125f, 0.125f, 0.125f, 0.125f);
    float base = (float)((idx * 4) & 7);
    ((float4*)(out + 262144))[idx] = make_float4(base, base + 1.f, base + 2.f, base + 3.f);
}

extern "C" void kernel_launch(void* const* d_in, const int* in_sizes, int n_in,
                              void* d_out, int out_size, void* d_ws, size_t ws_size,
                              hipStream_t stream) {
    const float* x    = (const float*)d_in[0];
    const float* phi  = (const float*)d_in[1];
    const float* bias = (const float*)d_in[2];
    float* out = (float*)d_out;

    // ws layout (float units):
    //   lp    @ 0        (2 x 1048576: two d-partials, [dq][b][k][s])
    //   pmax  @ 2097152  (2048)
    //   psum  @ 2099200  (2048)
    //   wbT   @ 2101248  (1048576 u16 = 524288 f)
    //   phiT  @ 2625536  (32768 u16 = 16384 f)
    //   part  @ 2641920  (8 x 262144)
    float* ws = (float*)d_ws;
    float* lp   = ws;
    float* pmax = ws + 2097152;
    float* psum = ws + 2099200;
    unsigned short* wbT  = (unsigned short*)(ws + 2101248);
    unsigned short* phiT = (unsigned short*)(ws + 2625536);
    float* part = ws + 2641920;
    float* pw_out = out + 524288;

    k0_phit<<<dim3(32), dim3(256), 0, stream>>>(phi, phiT);
    k1_logits<<<dim3(512), dim3(256), 0, stream>>>(x, phiT, bias, lp);
    k2a_partial<<<dim3(2048), dim3(256), 0, stream>>>(lp, pmax, psum);
    k2c_norm<<<dim3(256), dim3(256), 0, stream>>>(lp, pmax, psum, wbT, pw_out);
    k3_slots<<<dim3(512), dim3(256), 0, stream>>>(x, (const unsigned int*)wbT, part);
    k4_finalize<<<dim3(256), dim3(256), 0, stream>>>(part, out);
}